// Round 3
// baseline (246.633 us; speedup 1.0000x reference)
//
#include <hip/hip_runtime.h>
#include <math.h>

constexpr int kM0 = 16, kM1 = 8, kDim = 40, kNW = 576;
constexpr int kNodes = 10000, kEdges = 160000;

__device__ __forceinline__ float sspf(float x){
  // softplus(x) - ln2  (numerically stable)
  float ax = fabsf(x);
  return fmaxf(x, 0.f) + log1pf(expf(-ax)) - 0.69314718055994531f;
}

// ---------------- h = _lin(x, W1s, W1v) ----------------
__global__ void __launch_bounds__(256) k_prep(
    const float* __restrict__ x, const float* __restrict__ W1s,
    const float* __restrict__ W1v, float* __restrict__ h){
  int n = blockIdx.x*256 + threadIdx.x;
  if (n >= kNodes) return;
  const float* xp = x + n*kDim;
  float* hp = h + n*kDim;
  #pragma unroll
  for (int v=0; v<kM0; ++v){
    float acc = 0.f;
    #pragma unroll
    for (int u=0; u<kM0; ++u) acc += xp[u]*W1s[u*kM0+v];
    hp[v] = acc*0.25f;                       // 1/sqrt(16)
  }
  #pragma unroll
  for (int v=0; v<kM1; ++v){
    float a0=0.f,a1=0.f,a2=0.f;
    #pragma unroll
    for (int u=0; u<kM1; ++u){
      float wv = W1v[u*kM1+v];
      a0 += xp[16+u*3+0]*wv;
      a1 += xp[16+u*3+1]*wv;
      a2 += xp[16+u*3+2]*wv;
    }
    hp[16+v*3+0]=a0*0.35355339059327373f;    // 1/sqrt(8)
    hp[16+v*3+1]=a1*0.35355339059327373f;
    hp[16+v*3+2]=a2*0.35355339059327373f;
  }
}

// ---------------- WfcT[j][b] = Wfc[b][j]  (j = 0..575) ----------------
__global__ void __launch_bounds__(256) k_wfct(
    const float* __restrict__ Wfc, float* __restrict__ WfcT){
  int j = blockIdx.x*256 + threadIdx.x;
  if (j < kNW){
    #pragma unroll
    for (int b=0;b<8;++b) WfcT[j*8+b] = Wfc[b*kNW + j];
  }
}

// ---------------- CSR build: histogram / scan / fill ----------------
__global__ void __launch_bounds__(256) k_hist(
    const int* __restrict__ edst, int* __restrict__ cnt){
  int e = blockIdx.x*256 + threadIdx.x;
  if (e < kEdges) atomicAdd(&cnt[edst[e]], 1);
}

__global__ void __launch_bounds__(1024) k_scan(
    const int* __restrict__ cnt, int* __restrict__ offs, int* __restrict__ cursor){
  __shared__ int part[1024];
  int t = threadIdx.x;
  int base = t*10;                 // 1024*10 >= 10000
  int local[10];
  int s = 0;
  #pragma unroll
  for (int k=0;k<10;++k){
    int idx = base+k;
    int c = (idx<kNodes) ? cnt[idx] : 0;
    local[k] = s; s += c;
  }
  part[t] = s; __syncthreads();
  for (int d=1; d<1024; d<<=1){
    int v = part[t];
    int add = (t>=d) ? part[t-d] : 0;
    __syncthreads();
    part[t] = v + add;
    __syncthreads();
  }
  int excl = (t>0) ? part[t-1] : 0;
  #pragma unroll
  for (int k=0;k<10;++k){
    int idx = base+k;
    if (idx<kNodes){ int o = excl + local[k]; offs[idx]=o; cursor[idx]=o; }
  }
  if (t==1023) offs[kNodes] = part[1023];
}

__global__ void __launch_bounds__(256) k_fill(
    const int* __restrict__ edst, int* __restrict__ cursor, int* __restrict__ pos){
  int e = blockIdx.x*256 + threadIdx.x;
  if (e < kEdges){
    pos[e] = atomicAdd(&cursor[edst[e]], 1);
  }
}

// ---------------- per-edge messages, 2 edges/thread, dst-sorted store ----------------
__global__ void __launch_bounds__(128) k_edge(
    const float* __restrict__ er, const float* __restrict__ esh,
    const int* __restrict__ esrc, const int* __restrict__ pos,
    const float* __restrict__ h, const float* __restrict__ WfcT,
    float* __restrict__ msg){
  int base = (blockIdx.x*128 + threadIdx.x)*2;
  if (base >= kEdges) return;
  float r[2][8], sh0[2], sh1[2], sh2[2], sh3[2];
  const float* hp[2]; float* mp[2];
  #pragma unroll
  for (int k=0;k<2;++k){
    int e = base+k;
    float4 ra = *(const float4*)(er + (size_t)e*8);
    float4 rb = *(const float4*)(er + (size_t)e*8 + 4);
    r[k][0]=ra.x;r[k][1]=ra.y;r[k][2]=ra.z;r[k][3]=ra.w;
    r[k][4]=rb.x;r[k][5]=rb.y;r[k][6]=rb.z;r[k][7]=rb.w;
    float4 s4 = *(const float4*)(esh + (size_t)e*4);
    sh0[k]=s4.x; sh1[k]=s4.y; sh2[k]=s4.z; sh3[k]=s4.w;
    hp[k] = h + (size_t)esrc[e]*kDim;
    mp[k] = msg + (size_t)pos[e]*kDim;
  }

  float t00[2][16], t11[2][16], t01[2][8], tx[2][8], ty[2][8], tz[2][8];
  #pragma unroll
  for (int k=0;k<2;++k){
    #pragma unroll
    for (int w=0;w<16;++w){ t00[k][w]=0.f; t11[k][w]=0.f; }
    #pragma unroll
    for (int w=0;w<8;++w){ t01[k][w]=0.f; tx[k][w]=0.f; ty[k][w]=0.f; tz[k][w]=0.f; }
  }

  // ---- blocks 00 & 01 (share hs[u]; WfcT rows are wave-uniform scalar loads) ----
  #pragma unroll 1
  for (int u=0;u<16;++u){
    float xu0 = hp[0][u], xu1 = hp[1][u];
    const float* q = WfcT + u*16*8;
    #pragma unroll
    for (int w=0;w<16;++w){
      const float* qq = q + w*8;
      float a0 = r[0][0]*qq[0]+r[0][1]*qq[1]+r[0][2]*qq[2]+r[0][3]*qq[3]
               + r[0][4]*qq[4]+r[0][5]*qq[5]+r[0][6]*qq[6]+r[0][7]*qq[7];
      float a1 = r[1][0]*qq[0]+r[1][1]*qq[1]+r[1][2]*qq[2]+r[1][3]*qq[3]
               + r[1][4]*qq[4]+r[1][5]*qq[5]+r[1][6]*qq[6]+r[1][7]*qq[7];
      t00[0][w] += xu0*a0; t00[1][w] += xu1*a1;
    }
    const float* p = WfcT + (256 + u*8)*8;
    #pragma unroll
    for (int w=0;w<8;++w){
      const float* qq = p + w*8;
      float a0 = r[0][0]*qq[0]+r[0][1]*qq[1]+r[0][2]*qq[2]+r[0][3]*qq[3]
               + r[0][4]*qq[4]+r[0][5]*qq[5]+r[0][6]*qq[6]+r[0][7]*qq[7];
      float a1 = r[1][0]*qq[0]+r[1][1]*qq[1]+r[1][2]*qq[2]+r[1][3]*qq[3]
               + r[1][4]*qq[4]+r[1][5]*qq[5]+r[1][6]*qq[6]+r[1][7]*qq[7];
      t01[0][w] += xu0*a0; t01[1][w] += xu1*a1;
    }
  }
  // ---- blocks 10 & 11 (share hv[u]) ----
  #pragma unroll 1
  for (int u=0;u<8;++u){
    float v00=hp[0][16+u*3], v01=hp[0][16+u*3+1], v02=hp[0][16+u*3+2];
    float v10=hp[1][16+u*3], v11=hp[1][16+u*3+1], v12=hp[1][16+u*3+2];
    float au0 = v00*sh1[0] + v01*sh2[0] + v02*sh3[0];
    float au1 = v10*sh1[1] + v11*sh2[1] + v12*sh3[1];
    const float* p2 = WfcT + (384 + u*8)*8;
    #pragma unroll
    for (int w=0;w<8;++w){
      const float* qq = p2 + w*8;
      float a0 = r[0][0]*qq[0]+r[0][1]*qq[1]+r[0][2]*qq[2]+r[0][3]*qq[3]
               + r[0][4]*qq[4]+r[0][5]*qq[5]+r[0][6]*qq[6]+r[0][7]*qq[7];
      float a1 = r[1][0]*qq[0]+r[1][1]*qq[1]+r[1][2]*qq[2]+r[1][3]*qq[3]
               + r[1][4]*qq[4]+r[1][5]*qq[5]+r[1][6]*qq[6]+r[1][7]*qq[7];
      tx[0][w] += v00*a0; ty[0][w] += v01*a0; tz[0][w] += v02*a0;
      tx[1][w] += v10*a1; ty[1][w] += v11*a1; tz[1][w] += v12*a1;
    }
    const float* p3 = WfcT + (448 + u*16)*8;
    #pragma unroll
    for (int w=0;w<16;++w){
      const float* qq = p3 + w*8;
      float a0 = r[0][0]*qq[0]+r[0][1]*qq[1]+r[0][2]*qq[2]+r[0][3]*qq[3]
               + r[0][4]*qq[4]+r[0][5]*qq[5]+r[0][6]*qq[6]+r[0][7]*qq[7];
      float a1 = r[1][0]*qq[0]+r[1][1]*qq[1]+r[1][2]*qq[2]+r[1][3]*qq[3]
               + r[1][4]*qq[4]+r[1][5]*qq[5]+r[1][6]*qq[6]+r[1][7]*qq[7];
      t11[0][w] += au0*a0; t11[1][w] += au1*a1;
    }
  }

  constexpr float cs00 = 0.0625f;               // inv2/(sqrt8*4)
  constexpr float cs11 = 0.05103103630798288f;  // 1/sqrt(384)
  constexpr float cv01 = 0.0625f;
  constexpr float cv10 = 0.08838834764831845f;  // inv2/8

  #pragma unroll
  for (int k=0;k<2;++k){
    float m[40];
    #pragma unroll
    for (int w=0;w<16;++w) m[w] = sh0[k]*t00[k][w]*cs00 + t11[k][w]*cs11;
    #pragma unroll
    for (int w=0;w<8;++w){
      m[16+w*3+0] = sh1[k]*t01[k][w]*cv01 + sh0[k]*tx[k][w]*cv10;
      m[16+w*3+1] = sh2[k]*t01[k][w]*cv01 + sh0[k]*ty[k][w]*cv10;
      m[16+w*3+2] = sh3[k]*t01[k][w]*cv01 + sh0[k]*tz[k][w]*cv10;
    }
    #pragma unroll
    for (int o=0;o<40;o+=4)
      *(float4*)(mp[k]+o) = make_float4(m[o],m[o+1],m[o+2],m[o+3]);
  }
}

// ---------------- fused gather + linear2 + gate + residual ----------------
// 320 threads = 5 waves, 8 nodes/block. Gather: thread t -> (node t/40, comp t%40).
// Compute: waves 0-1 (t<128) = scalar outputs, waves 2-4 (t>=128) = vector outputs.
__global__ void __launch_bounds__(320) k_node(
    const float* __restrict__ x, const float* __restrict__ msg,
    const int* __restrict__ offs,
    const float* __restrict__ W2s, const float* __restrict__ W2v,
    const float* __restrict__ R00, const float* __restrict__ R01,
    const float* __restrict__ R10, const float* __restrict__ R11,
    float* __restrict__ out){
  __shared__ float sx[8][40];
  __shared__ float sa[8][40];
  int t = threadIdx.x;
  int nb = blockIdx.x*8;
  {
    int ns = t/40, c = t - ns*40;
    int n = nb + ns;
    int beg = offs[n], end = offs[n+1];
    float a = 0.f;
    for (int k=beg; k<end; ++k) a += msg[(size_t)k*kDim + c];  // contiguous rows
    sa[ns][c] = a * 0.25f;        // fold 1/deg = 1/sqrt(E/N) = 1/4
    sx[ns][c] = x[n*kDim + c];
  }
  __syncthreads();
  if (t < 128){
    // ---- scalar outputs: w = t&15 ----
    int ns = t>>4, w = t&15;
    int n = nb + ns;
    const float* ap = sa[ns];
    const float* xp = sx[ns];
    float hsum = 0.f;
    #pragma unroll
    for (int u=0;u<16;++u) hsum += ap[u]*W2s[u*16+w];
    hsum *= 0.25f;                 // 1/sqrt(16)
    float nrm = sqrtf(hsum*hsum + 1e-16f);
    float val = hsum/nrm*sspf(nrm);
    float xs[16];
    #pragma unroll
    for (int v=0;v<16;++v) xs[v] = xp[v];
    float r0 = 0.f;
    #pragma unroll 1
    for (int u=0;u<16;++u){
      float tacc = 0.f;
      #pragma unroll
      for (int v=0;v<16;++v) tacc += xs[v]*R00[(u*16+v)*16+w];
      r0 += xs[u]*tacc;
    }
    float xv[24];
    #pragma unroll
    for (int c2=0;c2<24;++c2) xv[c2] = xp[16+c2];
    float r1 = 0.f;
    #pragma unroll 1
    for (int u=0;u<8;++u){
      #pragma unroll
      for (int v=0;v<8;++v){
        float dot = xv[u*3]*xv[v*3] + xv[u*3+1]*xv[v*3+1] + xv[u*3+2]*xv[v*3+2];
        r1 += dot*R11[(u*8+v)*16+w];
      }
    }
    out[n*kDim + w] = val + 0.04419417382415922f*r0 + 0.05103103630798288f*r1;
  } else {
    // ---- vector outputs: cc = w*3+i ----
    int t2 = t - 128;
    int ns = t2/24, cc = t2 - ns*24;
    int w = cc/3, i = cc - w*3;
    int n = nb + ns;
    const float* ap = sa[ns] + 16;
    const float* xp = sx[ns];
    float h0=0.f,h1=0.f,h2=0.f;
    #pragma unroll
    for (int u=0;u<8;++u){
      float wv = W2v[u*8+w];
      h0 += ap[u*3+0]*wv; h1 += ap[u*3+1]*wv; h2 += ap[u*3+2]*wv;
    }
    const float sc = 0.35355339059327373f;   // 1/sqrt(8)
    h0*=sc; h1*=sc; h2*=sc;
    float nv = sqrtf(h0*h0+h1*h1+h2*h2 + 1e-16f);
    float hi = (i==0)?h0:((i==1)?h1:h2);
    float val = hi/nv*sspf(nv);
    float xs[16];
    #pragma unroll
    for (int v=0;v<16;++v) xs[v] = xp[v];
    float xvi[8];
    #pragma unroll
    for (int v=0;v<8;++v) xvi[v] = xp[16+v*3+i];
    float racc = 0.f;
    #pragma unroll 1
    for (int u=0;u<16;++u){
      float tacc=0.f;
      #pragma unroll
      for (int v=0;v<8;++v) tacc += xvi[v]*R01[(u*8+v)*8+w];
      racc += xs[u]*tacc;
    }
    #pragma unroll 1
    for (int u=0;u<8;++u){
      float tacc=0.f;
      #pragma unroll
      for (int v=0;v<16;++v) tacc += xs[v]*R10[(u*16+v)*8+w];
      racc += xvi[u]*tacc;
    }
    out[n*kDim + 16 + cc] = val + 0.0625f*racc;   // inv2/sqrt(128)
  }
}

extern "C" void kernel_launch(void* const* d_in, const int* in_sizes, int n_in,
                              void* d_out, int out_size, void* d_ws, size_t ws_size,
                              hipStream_t stream){
  const float* x   = (const float*)d_in[0];
  const float* er  = (const float*)d_in[1];
  const float* esh = (const float*)d_in[2];
  const int*   esrc= (const int*)d_in[3];
  const int*   edst= (const int*)d_in[4];
  const float* W1s = (const float*)d_in[6];
  const float* W1v = (const float*)d_in[7];
  const float* Wfc = (const float*)d_in[8];
  const float* W2s = (const float*)d_in[9];
  const float* W2v = (const float*)d_in[10];
  const float* R00 = (const float*)d_in[11];
  const float* R01 = (const float*)d_in[12];
  const float* R10 = (const float*)d_in[13];
  const float* R11 = (const float*)d_in[14];
  float* out = (float*)d_out;

  char* wsb = (char*)d_ws;
  float* h      = (float*)wsb;                                   // 400000 f
  float* msg    = h + (size_t)kNodes*kDim;                       // 6.4M f
  float* WfcT   = msg + (size_t)kEdges*kDim;                     // 4608 f
  int*   cnt    = (int*)(WfcT + kNW*8);                          // 10000
  int*   offs   = cnt + kNodes;                                  // 10001
  int*   cursor = offs + kNodes + 1;                             // 10000
  int*   pos    = cursor + kNodes;                               // 160000

  hipMemsetAsync(cnt, 0, kNodes*sizeof(int), stream);
  k_wfct<<<(kNW+255)/256, 256, 0, stream>>>(Wfc, WfcT);
  k_prep<<<(kNodes+255)/256, 256, 0, stream>>>(x, W1s, W1v, h);
  k_hist<<<(kEdges+255)/256, 256, 0, stream>>>(edst, cnt);
  k_scan<<<1, 1024, 0, stream>>>(cnt, offs, cursor);
  k_fill<<<(kEdges+255)/256, 256, 0, stream>>>(edst, cursor, pos);
  k_edge<<<(kEdges/2+127)/128, 128, 0, stream>>>(er, esh, esrc, pos, h, WfcT, msg);
  k_node<<<kNodes/8, 320, 0, stream>>>(x, msg, offs, W2s, W2v, R00, R01, R10, R11, out);
}

// Round 4
// 196.447 us; speedup vs baseline: 1.2555x; 1.2555x over previous
//
#include <hip/hip_runtime.h>
#include <math.h>

constexpr int kM0 = 16, kM1 = 8, kDim = 40, kNW = 576;
constexpr int kNodes = 10000, kEdges = 160000;
constexpr int kNB = 24;   // nodes per k_node block (960 threads = 15 waves)

__device__ __forceinline__ float sspf(float x){
  // softplus(x) - ln2  (numerically stable)
  float ax = fabsf(x);
  return fmaxf(x, 0.f) + log1pf(expf(-ax)) - 0.69314718055994531f;
}

// ---------------- fused: Wfc transpose + h=_lin1(x) + dst histogram ----------------
// grid exactly kEdges threads
__global__ void __launch_bounds__(256) k_pre(
    const float* __restrict__ x, const float* __restrict__ W1s,
    const float* __restrict__ W1v, const float* __restrict__ Wfc,
    const int* __restrict__ edst,
    float* __restrict__ h, float* __restrict__ WfcT, int* __restrict__ cnt){
  int t = blockIdx.x*256 + threadIdx.x;
  atomicAdd(&cnt[edst[t]], 1);                 // t < kEdges always (exact grid)
  if (t < kNW){
    #pragma unroll
    for (int b=0;b<8;++b) WfcT[t*8+b] = Wfc[b*kNW + t];
  }
  if (t < kNodes){
    const float* xp = x + (size_t)t*kDim;
    float* hp = h + (size_t)t*kDim;
    #pragma unroll
    for (int v=0; v<kM0; ++v){
      float acc = 0.f;
      #pragma unroll
      for (int u=0; u<kM0; ++u) acc += xp[u]*W1s[u*kM0+v];
      hp[v] = acc*0.25f;                       // 1/sqrt(16)
    }
    #pragma unroll
    for (int v=0; v<kM1; ++v){
      float a0=0.f,a1=0.f,a2=0.f;
      #pragma unroll
      for (int u=0; u<kM1; ++u){
        float wv = W1v[u*kM1+v];
        a0 += xp[16+u*3+0]*wv;
        a1 += xp[16+u*3+1]*wv;
        a2 += xp[16+u*3+2]*wv;
      }
      hp[16+v*3+0]=a0*0.35355339059327373f;    // 1/sqrt(8)
      hp[16+v*3+1]=a1*0.35355339059327373f;
      hp[16+v*3+2]=a2*0.35355339059327373f;
    }
  }
}

// ---------------- CSR scan + fill ----------------
__global__ void __launch_bounds__(1024) k_scan(
    const int* __restrict__ cnt, int* __restrict__ offs, int* __restrict__ cursor){
  __shared__ int part[1024];
  int t = threadIdx.x;
  int base = t*10;                 // 1024*10 >= 10000
  int local[10];
  int s = 0;
  #pragma unroll
  for (int k=0;k<10;++k){
    int idx = base+k;
    int c = (idx<kNodes) ? cnt[idx] : 0;
    local[k] = s; s += c;
  }
  part[t] = s; __syncthreads();
  for (int d=1; d<1024; d<<=1){
    int v = part[t];
    int add = (t>=d) ? part[t-d] : 0;
    __syncthreads();
    part[t] = v + add;
    __syncthreads();
  }
  int excl = (t>0) ? part[t-1] : 0;
  #pragma unroll
  for (int k=0;k<10;++k){
    int idx = base+k;
    if (idx<kNodes){ int o = excl + local[k]; offs[idx]=o; cursor[idx]=o; }
  }
  if (t==1023) offs[kNodes] = part[1023];
}

__global__ void __launch_bounds__(256) k_fill(
    const int* __restrict__ edst, int* __restrict__ cursor, int* __restrict__ pos){
  int e = blockIdx.x*256 + threadIdx.x;
  if (e < kEdges) pos[e] = atomicAdd(&cursor[edst[e]], 1);
}

// ---------------- per-edge messages: 4 threads (one per wave) per edge ----------------
// wave q of each block computes w-quarter q; Wfc indices stay wave-uniform -> s_load.
__global__ void __launch_bounds__(256) k_edge(
    const float* __restrict__ er, const float* __restrict__ esh,
    const int* __restrict__ esrc, const int* __restrict__ pos,
    const float* __restrict__ h, const float* __restrict__ WfcT,
    float* __restrict__ msg){
  int lane = threadIdx.x & 63;
  int q = __builtin_amdgcn_readfirstlane(threadIdx.x >> 6);   // 0..3, wave-uniform
  int e = blockIdx.x*64 + lane;                               // exact grid: 2500*64
  float4 ra = *(const float4*)(er + (size_t)e*8);
  float4 rb = *(const float4*)(er + (size_t)e*8 + 4);
  const float r0=ra.x,r1=ra.y,r2=ra.z,r3=ra.w,r4=rb.x,r5=rb.y,r6=rb.z,r7=rb.w;
  float4 s4 = *(const float4*)(esh + (size_t)e*4);
  const float* hp = h + (size_t)esrc[e]*kDim;
  float* mp = msg + (size_t)pos[e]*kDim;

#define DOT8(p) ((p)[0]*r0+(p)[1]*r1+(p)[2]*r2+(p)[3]*r3+(p)[4]*r4+(p)[5]*r5+(p)[6]*r6+(p)[7]*r7)

  const int w0 = q*4;     // scalar w-range [w0, w0+4)
  const int w2 = q*2;     // vector w-range [w2, w2+2)
  float t00[4]={0,0,0,0}, t11[4]={0,0,0,0};
  float t01[2]={0,0}, tx[2]={0,0}, ty[2]={0,0}, tz[2]={0,0};

  #pragma unroll
  for (int u=0;u<16;++u){
    float xu = hp[u];
    const float* p0 = WfcT + (size_t)(u*16 + w0)*8;
    #pragma unroll
    for (int wi=0;wi<4;++wi) t00[wi] += xu*DOT8(p0 + wi*8);
    const float* p1 = WfcT + (size_t)(256 + u*8 + w2)*8;
    #pragma unroll
    for (int wi=0;wi<2;++wi) t01[wi] += xu*DOT8(p1 + wi*8);
  }
  #pragma unroll
  for (int u=0;u<8;++u){
    float v0=hp[16+u*3], v1=hp[16+u*3+1], v2=hp[16+u*3+2];
    float au = v0*s4.y + v1*s4.z + v2*s4.w;
    const float* p3 = WfcT + (size_t)(448 + u*16 + w0)*8;
    #pragma unroll
    for (int wi=0;wi<4;++wi) t11[wi] += au*DOT8(p3 + wi*8);
    const float* p2 = WfcT + (size_t)(384 + u*8 + w2)*8;
    #pragma unroll
    for (int wi=0;wi<2;++wi){
      float a = DOT8(p2 + wi*8);
      tx[wi] += v0*a; ty[wi] += v1*a; tz[wi] += v2*a;
    }
  }
#undef DOT8

  constexpr float cs00 = 0.0625f;               // inv2/(sqrt8*4)
  constexpr float cs11 = 0.05103103630798288f;  // 1/sqrt(384)
  constexpr float cv01 = 0.0625f;
  constexpr float cv10 = 0.08838834764831845f;  // inv2/8

  float4 ms;
  ms.x = s4.x*t00[0]*cs00 + t11[0]*cs11;
  ms.y = s4.x*t00[1]*cs00 + t11[1]*cs11;
  ms.z = s4.x*t00[2]*cs00 + t11[2]*cs11;
  ms.w = s4.x*t00[3]*cs00 + t11[3]*cs11;
  *(float4*)(mp + w0) = ms;

  // vector chunk: 6 floats at mp + 16 + 6q  (8B-aligned)
  float va = t01[0]*cv01, vb = t01[1]*cv01, sc0 = s4.x*cv10;
  float m0 = s4.y*va + tx[0]*sc0;
  float m1 = s4.z*va + ty[0]*sc0;
  float m2 = s4.w*va + tz[0]*sc0;
  float m3 = s4.y*vb + tx[1]*sc0;
  float m4 = s4.z*vb + ty[1]*sc0;
  float m5 = s4.w*vb + tz[1]*sc0;
  float* vp = mp + 16 + w2*3;
  *(float2*)(vp+0) = make_float2(m0, m1);
  *(float2*)(vp+2) = make_float2(m2, m3);
  *(float2*)(vp+4) = make_float2(m4, m5);
}

// ---------------- fused gather + linear2 + gate + residual, LDS-staged weights ----------------
__global__ void __launch_bounds__(960) k_node(
    const float* __restrict__ x, const float* __restrict__ msg,
    const int* __restrict__ offs,
    const float* __restrict__ W2s, const float* __restrict__ W2v,
    const float* __restrict__ R00, const float* __restrict__ R01,
    const float* __restrict__ R10, const float* __restrict__ R11,
    float* __restrict__ out){
  __shared__ float sR00[4096], sR01[1024], sR10[1024], sR11[1024];
  __shared__ float sW2s[256], sW2v[64];
  __shared__ float sx[kNB][40], sa[kNB][40];
  int t = threadIdx.x;
  // ---- stage weights (float4, coalesced) ----
  for (int i=t; i<1024; i+=960) ((float4*)sR00)[i] = ((const float4*)R00)[i];
  if (t < 256){
    ((float4*)sR01)[t] = ((const float4*)R01)[t];
    ((float4*)sR10)[t] = ((const float4*)R10)[t];
    ((float4*)sR11)[t] = ((const float4*)R11)[t];
  }
  if (t < 64) ((float4*)sW2s)[t] = ((const float4*)W2s)[t];
  if (t < 16) ((float4*)sW2v)[t] = ((const float4*)W2v)[t];
  // ---- gather ----
  int nb = blockIdx.x*kNB;
  {
    int ns = t/40, c = t - ns*40, n = nb + ns;
    float a = 0.f, xval = 0.f;
    if (n < kNodes){
      int beg = offs[n], end = offs[n+1];
      for (int k=beg; k<end; ++k) a += msg[(size_t)k*kDim + c];
      xval = x[(size_t)n*kDim + c];
    }
    sa[ns][c] = a*0.25f;          // fold 1/deg = 1/4
    sx[ns][c] = xval;
  }
  __syncthreads();
  if (t < kNB*16){
    // ---- scalar outputs ----
    int ns = t>>4, w = t&15, n = nb+ns;
    const float* ap = sa[ns];
    const float* xp = sx[ns];
    float hsum = 0.f;
    #pragma unroll
    for (int u=0;u<16;++u) hsum += ap[u]*sW2s[u*16+w];
    hsum *= 0.25f;                 // 1/sqrt(16)
    float nrm = sqrtf(hsum*hsum + 1e-16f);
    float val = hsum/nrm*sspf(nrm);
    float xs[16];
    #pragma unroll
    for (int v=0;v<16;++v) xs[v] = xp[v];
    float r0 = 0.f;
    #pragma unroll
    for (int u=0;u<16;++u){
      float tacc = 0.f;
      #pragma unroll
      for (int v=0;v<16;++v) tacc += xs[v]*sR00[(u*16+v)*16+w];
      r0 += xs[u]*tacc;
    }
    float xv[24];
    #pragma unroll
    for (int c2=0;c2<24;++c2) xv[c2] = xp[16+c2];
    float r1 = 0.f;
    #pragma unroll
    for (int u=0;u<8;++u){
      #pragma unroll
      for (int v=0;v<8;++v){
        float dot = xv[u*3]*xv[v*3] + xv[u*3+1]*xv[v*3+1] + xv[u*3+2]*xv[v*3+2];
        r1 += dot*sR11[(u*8+v)*16+w];
      }
    }
    if (n < kNodes)
      out[(size_t)n*kDim + w] = val + 0.04419417382415922f*r0 + 0.05103103630798288f*r1;
  } else {
    // ---- vector outputs ----
    int t2 = t - kNB*16;
    int ns = t2/24, cc = t2 - ns*24, w = cc/3, i = cc - w*3, n = nb+ns;
    const float* ap = sa[ns] + 16;
    const float* xp = sx[ns];
    float h0=0.f,h1=0.f,h2=0.f;
    #pragma unroll
    for (int u=0;u<8;++u){
      float wv = sW2v[u*8+w];
      h0 += ap[u*3+0]*wv; h1 += ap[u*3+1]*wv; h2 += ap[u*3+2]*wv;
    }
    const float sc = 0.35355339059327373f;   // 1/sqrt(8)
    h0*=sc; h1*=sc; h2*=sc;
    float nv = sqrtf(h0*h0+h1*h1+h2*h2 + 1e-16f);
    float hi = (i==0)?h0:((i==1)?h1:h2);
    float val = hi/nv*sspf(nv);
    float xs[16];
    #pragma unroll
    for (int v=0;v<16;++v) xs[v] = xp[v];
    float xvi[8];
    #pragma unroll
    for (int v=0;v<8;++v) xvi[v] = xp[16+v*3+i];
    float racc = 0.f;
    #pragma unroll
    for (int u=0;u<16;++u){
      float tacc=0.f;
      #pragma unroll
      for (int v=0;v<8;++v) tacc += xvi[v]*sR01[(u*8+v)*8+w];
      racc += xs[u]*tacc;
    }
    #pragma unroll
    for (int u=0;u<8;++u){
      float tacc=0.f;
      #pragma unroll
      for (int v=0;v<16;++v) tacc += xs[v]*sR10[(u*16+v)*8+w];
      racc += xvi[u]*tacc;
    }
    if (n < kNodes)
      out[(size_t)n*kDim + 16 + cc] = val + 0.0625f*racc;   // inv2/sqrt(128)
  }
}

extern "C" void kernel_launch(void* const* d_in, const int* in_sizes, int n_in,
                              void* d_out, int out_size, void* d_ws, size_t ws_size,
                              hipStream_t stream){
  const float* x   = (const float*)d_in[0];
  const float* er  = (const float*)d_in[1];
  const float* esh = (const float*)d_in[2];
  const int*   esrc= (const int*)d_in[3];
  const int*   edst= (const int*)d_in[4];
  const float* W1s = (const float*)d_in[6];
  const float* W1v = (const float*)d_in[7];
  const float* Wfc = (const float*)d_in[8];
  const float* W2s = (const float*)d_in[9];
  const float* W2v = (const float*)d_in[10];
  const float* R00 = (const float*)d_in[11];
  const float* R01 = (const float*)d_in[12];
  const float* R10 = (const float*)d_in[13];
  const float* R11 = (const float*)d_in[14];
  float* out = (float*)d_out;

  char* wsb = (char*)d_ws;
  float* h      = (float*)wsb;                                   // 400000 f
  float* msg    = h + (size_t)kNodes*kDim;                       // 6.4M f
  float* WfcT   = msg + (size_t)kEdges*kDim;                     // 4608 f
  int*   cnt    = (int*)(WfcT + kNW*8);                          // 10000
  int*   offs   = cnt + kNodes;                                  // 10001
  int*   cursor = offs + kNodes + 1;                             // 10000
  int*   pos    = cursor + kNodes;                               // 160000

  hipMemsetAsync(cnt, 0, kNodes*sizeof(int), stream);
  k_pre<<<kEdges/256, 256, 0, stream>>>(x, W1s, W1v, Wfc, edst, h, WfcT, cnt);
  k_scan<<<1, 1024, 0, stream>>>(cnt, offs, cursor);
  k_fill<<<(kEdges+255)/256, 256, 0, stream>>>(edst, cursor, pos);
  k_edge<<<kEdges/64, 256, 0, stream>>>(er, esh, esrc, pos, h, WfcT, msg);
  k_node<<<(kNodes+kNB-1)/kNB, 960, 0, stream>>>(x, msg, offs, W2s, W2v, R00, R01, R10, R11, out);
}

// Round 5
// 172.033 us; speedup vs baseline: 1.4336x; 1.1419x over previous
//
#include <hip/hip_runtime.h>
#include <math.h>

constexpr int kM0 = 16, kM1 = 8, kDim = 40, kNW = 576;
constexpr int kNodes = 10000, kEdges = 160000;
constexpr int kCap = 96;  // bucket capacity; deg ~ Poisson(16), 96 = +20 sigma
constexpr int kNB = 24;   // nodes per k_node block (960 threads = 15 waves)

__device__ __forceinline__ float sspf(float x){
  // softplus(x) - ln2  (numerically stable)
  float ax = fabsf(x);
  return fmaxf(x, 0.f) + log1pf(expf(-ax)) - 0.69314718055994531f;
}

// ---- fused: dst histogram (-> per-edge slot) + Wfc transpose + h = _lin1(x) ----
// grid exactly kEdges threads (625 * 256)
__global__ void __launch_bounds__(256) k_pre(
    const float* __restrict__ x, const float* __restrict__ W1s,
    const float* __restrict__ W1v, const float* __restrict__ Wfc,
    const int* __restrict__ edst,
    float* __restrict__ h, float* __restrict__ WfcT,
    int* __restrict__ cnt, int* __restrict__ posw){
  int t = blockIdx.x*256 + threadIdx.x;
  posw[t] = atomicAdd(&cnt[edst[t]], 1);       // t < kEdges always (exact grid)
  if (t < kNW){
    #pragma unroll
    for (int b=0;b<8;++b) WfcT[t*8+b] = Wfc[b*kNW + t];
  }
  if (t < kNodes){
    const float* xp = x + (size_t)t*kDim;
    float* hp = h + (size_t)t*kDim;
    #pragma unroll
    for (int v=0; v<kM0; ++v){
      float acc = 0.f;
      #pragma unroll
      for (int u=0; u<kM0; ++u) acc += xp[u]*W1s[u*kM0+v];
      hp[v] = acc*0.25f;                       // 1/sqrt(16)
    }
    #pragma unroll
    for (int v=0; v<kM1; ++v){
      float a0=0.f,a1=0.f,a2=0.f;
      #pragma unroll
      for (int u=0; u<kM1; ++u){
        float wv = W1v[u*kM1+v];
        a0 += xp[16+u*3+0]*wv;
        a1 += xp[16+u*3+1]*wv;
        a2 += xp[16+u*3+2]*wv;
      }
      hp[16+v*3+0]=a0*0.35355339059327373f;    // 1/sqrt(8)
      hp[16+v*3+1]=a1*0.35355339059327373f;
      hp[16+v*3+2]=a2*0.35355339059327373f;
    }
  }
}

// ---------------- per-edge messages: 4 threads (one per wave) per edge ----------------
// wave q of each block computes w-quarter q; Wfc indices stay wave-uniform -> s_load.
__global__ void __launch_bounds__(256) k_edge(
    const float* __restrict__ er, const float* __restrict__ esh,
    const int* __restrict__ esrc, const int* __restrict__ edst,
    const int* __restrict__ posw,
    const float* __restrict__ h, const float* __restrict__ WfcT,
    float* __restrict__ msg){
  int lane = threadIdx.x & 63;
  int q = __builtin_amdgcn_readfirstlane(threadIdx.x >> 6);   // 0..3, wave-uniform
  int e = blockIdx.x*64 + lane;                               // exact grid: 2500*64
  float4 ra = *(const float4*)(er + (size_t)e*8);
  float4 rb = *(const float4*)(er + (size_t)e*8 + 4);
  const float r0=ra.x,r1=ra.y,r2=ra.z,r3=ra.w,r4=rb.x,r5=rb.y,r6=rb.z,r7=rb.w;
  float4 s4 = *(const float4*)(esh + (size_t)e*4);
  const float* hp = h + (size_t)esrc[e]*kDim;
  float* mp = msg + ((size_t)edst[e]*kCap + posw[e])*kDim;

#define DOT8(p) ((p)[0]*r0+(p)[1]*r1+(p)[2]*r2+(p)[3]*r3+(p)[4]*r4+(p)[5]*r5+(p)[6]*r6+(p)[7]*r7)

  const int w0 = q*4;     // scalar w-range [w0, w0+4)
  const int w2 = q*2;     // vector w-range [w2, w2+2)
  float t00[4]={0,0,0,0}, t11[4]={0,0,0,0};
  float t01[2]={0,0}, tx[2]={0,0}, ty[2]={0,0}, tz[2]={0,0};

  #pragma unroll
  for (int u=0;u<16;++u){
    float xu = hp[u];
    const float* p0 = WfcT + (size_t)(u*16 + w0)*8;
    #pragma unroll
    for (int wi=0;wi<4;++wi) t00[wi] += xu*DOT8(p0 + wi*8);
    const float* p1 = WfcT + (size_t)(256 + u*8 + w2)*8;
    #pragma unroll
    for (int wi=0;wi<2;++wi) t01[wi] += xu*DOT8(p1 + wi*8);
  }
  #pragma unroll
  for (int u=0;u<8;++u){
    float v0=hp[16+u*3], v1=hp[16+u*3+1], v2=hp[16+u*3+2];
    float au = v0*s4.y + v1*s4.z + v2*s4.w;
    const float* p3 = WfcT + (size_t)(448 + u*16 + w0)*8;
    #pragma unroll
    for (int wi=0;wi<4;++wi) t11[wi] += au*DOT8(p3 + wi*8);
    const float* p2 = WfcT + (size_t)(384 + u*8 + w2)*8;
    #pragma unroll
    for (int wi=0;wi<2;++wi){
      float a = DOT8(p2 + wi*8);
      tx[wi] += v0*a; ty[wi] += v1*a; tz[wi] += v2*a;
    }
  }
#undef DOT8

  constexpr float cs00 = 0.0625f;               // inv2/(sqrt8*4)
  constexpr float cs11 = 0.05103103630798288f;  // 1/sqrt(384)
  constexpr float cv01 = 0.0625f;
  constexpr float cv10 = 0.08838834764831845f;  // inv2/8

  float4 ms;
  ms.x = s4.x*t00[0]*cs00 + t11[0]*cs11;
  ms.y = s4.x*t00[1]*cs00 + t11[1]*cs11;
  ms.z = s4.x*t00[2]*cs00 + t11[2]*cs11;
  ms.w = s4.x*t00[3]*cs00 + t11[3]*cs11;
  *(float4*)(mp + w0) = ms;

  // vector chunk: 6 floats at mp + 16 + 6q  (8B-aligned)
  float va = t01[0]*cv01, vb = t01[1]*cv01, sc0 = s4.x*cv10;
  float m0 = s4.y*va + tx[0]*sc0;
  float m1 = s4.z*va + ty[0]*sc0;
  float m2 = s4.w*va + tz[0]*sc0;
  float m3 = s4.y*vb + tx[1]*sc0;
  float m4 = s4.z*vb + ty[1]*sc0;
  float m5 = s4.w*vb + tz[1]*sc0;
  float* vp = mp + 16 + w2*3;
  *(float2*)(vp+0) = make_float2(m0, m1);
  *(float2*)(vp+2) = make_float2(m2, m3);
  *(float2*)(vp+4) = make_float2(m4, m5);
}

// ---------------- fused gather + linear2 + gate + residual, LDS-staged weights ----------------
__global__ void __launch_bounds__(960) k_node(
    const float* __restrict__ x, const float* __restrict__ msg,
    const int* __restrict__ cnt,
    const float* __restrict__ W2s, const float* __restrict__ W2v,
    const float* __restrict__ R00, const float* __restrict__ R01,
    const float* __restrict__ R10, const float* __restrict__ R11,
    float* __restrict__ out){
  __shared__ float sR00[4096], sR01[1024], sR10[1024], sR11[1024];
  __shared__ float sW2s[256], sW2v[64];
  __shared__ float sx[kNB][40], sa[kNB][40];
  int t = threadIdx.x;
  // ---- stage weights (float4, coalesced) ----
  for (int i=t; i<1024; i+=960) ((float4*)sR00)[i] = ((const float4*)R00)[i];
  if (t < 256){
    ((float4*)sR01)[t] = ((const float4*)R01)[t];
    ((float4*)sR10)[t] = ((const float4*)R10)[t];
    ((float4*)sR11)[t] = ((const float4*)R11)[t];
  }
  if (t < 64) ((float4*)sW2s)[t] = ((const float4*)W2s)[t];
  if (t < 16) ((float4*)sW2v)[t] = ((const float4*)W2v)[t];
  // ---- gather from bucket ----
  int nb = blockIdx.x*kNB;
  {
    int ns = t/40, c = t - ns*40, n = nb + ns;
    float a = 0.f, xval = 0.f;
    if (n < kNodes){
      int deg = cnt[n];
      const float* bp = msg + (size_t)n*kCap*kDim + c;
      for (int k=0; k<deg; ++k) a += bp[(size_t)k*kDim];
      xval = x[(size_t)n*kDim + c];
    }
    sa[ns][c] = a*0.25f;          // fold 1/deg = 1/4
    sx[ns][c] = xval;
  }
  __syncthreads();
  if (t < kNB*16){
    // ---- scalar outputs ----
    int ns = t>>4, w = t&15, n = nb+ns;
    const float* ap = sa[ns];
    const float* xp = sx[ns];
    float hsum = 0.f;
    #pragma unroll
    for (int u=0;u<16;++u) hsum += ap[u]*sW2s[u*16+w];
    hsum *= 0.25f;                 // 1/sqrt(16)
    float nrm = sqrtf(hsum*hsum + 1e-16f);
    float val = hsum/nrm*sspf(nrm);
    float xs[16];
    #pragma unroll
    for (int v=0;v<16;++v) xs[v] = xp[v];
    float r0 = 0.f;
    #pragma unroll
    for (int u=0;u<16;++u){
      float tacc = 0.f;
      #pragma unroll
      for (int v=0;v<16;++v) tacc += xs[v]*sR00[(u*16+v)*16+w];
      r0 += xs[u]*tacc;
    }
    float xv[24];
    #pragma unroll
    for (int c2=0;c2<24;++c2) xv[c2] = xp[16+c2];
    float r1 = 0.f;
    #pragma unroll
    for (int u=0;u<8;++u){
      #pragma unroll
      for (int v=0;v<8;++v){
        float dot = xv[u*3]*xv[v*3] + xv[u*3+1]*xv[v*3+1] + xv[u*3+2]*xv[v*3+2];
        r1 += dot*sR11[(u*8+v)*16+w];
      }
    }
    if (n < kNodes)
      out[(size_t)n*kDim + w] = val + 0.04419417382415922f*r0 + 0.05103103630798288f*r1;
  } else {
    // ---- vector outputs ----
    int t2 = t - kNB*16;
    int ns = t2/24, cc = t2 - ns*24, w = cc/3, i = cc - w*3, n = nb+ns;
    const float* ap = sa[ns] + 16;
    const float* xp = sx[ns];
    float h0=0.f,h1=0.f,h2=0.f;
    #pragma unroll
    for (int u=0;u<8;++u){
      float wv = sW2v[u*8+w];
      h0 += ap[u*3+0]*wv; h1 += ap[u*3+1]*wv; h2 += ap[u*3+2]*wv;
    }
    const float sc = 0.35355339059327373f;   // 1/sqrt(8)
    h0*=sc; h1*=sc; h2*=sc;
    float nv = sqrtf(h0*h0+h1*h1+h2*h2 + 1e-16f);
    float hi = (i==0)?h0:((i==1)?h1:h2);
    float val = hi/nv*sspf(nv);
    float xs[16];
    #pragma unroll
    for (int v=0;v<16;++v) xs[v] = xp[v];
    float xvi[8];
    #pragma unroll
    for (int v=0;v<8;++v) xvi[v] = xp[16+v*3+i];
    float racc = 0.f;
    #pragma unroll
    for (int u=0;u<16;++u){
      float tacc=0.f;
      #pragma unroll
      for (int v=0;v<8;++v) tacc += xvi[v]*sR01[(u*8+v)*8+w];
      racc += xs[u]*tacc;
    }
    #pragma unroll
    for (int u=0;u<8;++u){
      float tacc=0.f;
      #pragma unroll
      for (int v=0;v<16;++v) tacc += xs[v]*sR10[(u*16+v)*8+w];
      racc += xvi[u]*tacc;
    }
    if (n < kNodes)
      out[(size_t)n*kDim + 16 + cc] = val + 0.0625f*racc;   // inv2/sqrt(128)
  }
}

extern "C" void kernel_launch(void* const* d_in, const int* in_sizes, int n_in,
                              void* d_out, int out_size, void* d_ws, size_t ws_size,
                              hipStream_t stream){
  const float* x   = (const float*)d_in[0];
  const float* er  = (const float*)d_in[1];
  const float* esh = (const float*)d_in[2];
  const int*   esrc= (const int*)d_in[3];
  const int*   edst= (const int*)d_in[4];
  const float* W1s = (const float*)d_in[6];
  const float* W1v = (const float*)d_in[7];
  const float* Wfc = (const float*)d_in[8];
  const float* W2s = (const float*)d_in[9];
  const float* W2v = (const float*)d_in[10];
  const float* R00 = (const float*)d_in[11];
  const float* R01 = (const float*)d_in[12];
  const float* R10 = (const float*)d_in[13];
  const float* R11 = (const float*)d_in[14];
  float* out = (float*)d_out;

  // ws layout (16B-aligned blocks)
  char* wsb = (char*)d_ws;
  float* h    = (float*)wsb;                                     // 400,000 f (1.6 MB)
  float* msg  = h + (size_t)kNodes*kDim;                         // 10000*96*40 f (153.6 MB)
  float* WfcT = msg + (size_t)kNodes*kCap*kDim;                  // 4,608 f
  int*   cnt  = (int*)(WfcT + (size_t)kNW*8);                    // 10,000
  int*   posw = cnt + kNodes;                                    // 160,000

  hipMemsetAsync(cnt, 0, kNodes*sizeof(int), stream);
  k_pre<<<kEdges/256, 256, 0, stream>>>(x, W1s, W1v, Wfc, edst, h, WfcT, cnt, posw);
  k_edge<<<kEdges/64, 256, 0, stream>>>(er, esh, esrc, edst, posw, h, WfcT, msg);
  k_node<<<(kNodes+kNB-1)/kNB, 960, 0, stream>>>(x, msg, cnt, W2s, W2v, R00, R01, R10, R11, out);
}